// Round 1
// baseline (117.668 us; speedup 1.0000x reference)
//
#include <hip/hip_runtime.h>

#define HW    12544   // 112*112
#define HW4   3136    // HW/4
#define NCH   64      // channels
#define NB    64      // batch
#define NG    4       // clusters
#define EPSF  1e-5f

// ws layout (floats): [0,256)  S[g*NCH+c]
//                     [256,512) SS[g*NCH+c]
//                     [512,516) cnt[g]

__global__ void cn_init(const int* __restrict__ labels, float* __restrict__ ws) {
    int t = threadIdx.x;
    if (t < 512) ws[t] = 0.0f;
    if (t < NG) {
        int cnt = 0;
        for (int b = 0; b < NB; ++b) cnt += (labels[b] == t) ? 1 : 0;
        ws[512 + t] = (float)cnt;
    }
}

__global__ __launch_bounds__(256) void cn_stats(const float* __restrict__ x,
                                                const int* __restrict__ labels,
                                                float* __restrict__ ws) {
    int p = blockIdx.x;            // plane index = b*NCH + c
    int b = p >> 6;
    int c = p & 63;
    const float4* xp = (const float4*)(x + (size_t)p * HW);
    float s = 0.0f, ss = 0.0f;
    for (int i = threadIdx.x; i < HW4; i += 256) {
        float4 v = xp[i];
        s  += v.x + v.y + v.z + v.w;
        ss += v.x * v.x + v.y * v.y + v.z * v.z + v.w * v.w;
    }
    // wave-64 butterfly reduce
    #pragma unroll
    for (int off = 32; off > 0; off >>= 1) {
        s  += __shfl_down(s, off, 64);
        ss += __shfl_down(ss, off, 64);
    }
    __shared__ float sh_s[4], sh_ss[4];
    int lane = threadIdx.x & 63;
    int wave = threadIdx.x >> 6;
    if (lane == 0) { sh_s[wave] = s; sh_ss[wave] = ss; }
    __syncthreads();
    if (threadIdx.x == 0) {
        float ts  = sh_s[0]  + sh_s[1]  + sh_s[2]  + sh_s[3];
        float tss = sh_ss[0] + sh_ss[1] + sh_ss[2] + sh_ss[3];
        int g = labels[b];
        atomicAdd(&ws[g * NCH + c], ts);
        atomicAdd(&ws[256 + g * NCH + c], tss);
    }
}

__global__ __launch_bounds__(256) void cn_norm(const float* __restrict__ x,
                                               const int* __restrict__ labels,
                                               const float* __restrict__ rmean,
                                               const float* __restrict__ rvar,
                                               const float* __restrict__ wgt,
                                               const float* __restrict__ bia,
                                               const float* __restrict__ ws,
                                               float* __restrict__ out) {
    int p = blockIdx.x;
    int b = p >> 6;
    int c = p & 63;
    int g = labels[b];
    float cntf = ws[512 + g];
    float N    = cntf * (float)HW;
    float S    = ws[g * NCH + c];
    float SS   = ws[256 + g * NCH + c];
    float mean = S / fmaxf(N, 1.0f);
    float var  = (SS - N * mean * mean) / fmaxf(N - 1.0f, 1.0f);
    float mu   = 0.2f * mean + 0.8f * rmean[c];
    float vb   = 0.2f * var  + 0.8f * rvar[c];
    float scale = rsqrtf(vb + EPSF) * wgt[c];
    float shift = bia[c] - mu * scale;
    const float4* xp = (const float4*)(x + (size_t)p * HW);
    float4*       op = (float4*)(out + (size_t)p * HW);
    for (int i = threadIdx.x; i < HW4; i += 256) {
        float4 v = xp[i];
        float4 o;
        o.x = v.x * scale + shift;
        o.y = v.y * scale + shift;
        o.z = v.z * scale + shift;
        o.w = v.w * scale + shift;
        op[i] = o;
    }
}

extern "C" void kernel_launch(void* const* d_in, const int* in_sizes, int n_in,
                              void* d_out, int out_size, void* d_ws, size_t ws_size,
                              hipStream_t stream) {
    const float* x      = (const float*)d_in[0];
    const float* rmean  = (const float*)d_in[1];
    const float* rvar   = (const float*)d_in[2];
    const float* wgt    = (const float*)d_in[3];
    const float* bia    = (const float*)d_in[4];
    const int*   labels = (const int*)d_in[5];
    float* out = (float*)d_out;
    float* ws  = (float*)d_ws;

    const int planes = NB * NCH; // 4096

    cn_init<<<1, 512, 0, stream>>>(labels, ws);
    cn_stats<<<planes, 256, 0, stream>>>(x, labels, ws);
    cn_norm<<<planes, 256, 0, stream>>>(x, labels, rmean, rvar, wgt, bia, ws, out);
}

// Round 3
// 96.714 us; speedup vs baseline: 1.2167x; 1.2167x over previous
//
#include <hip/hip_runtime.h>

#define HW    12544   // 112*112
#define HW4   3136    // HW/4
#define NCH   64      // channels
#define NB    64      // batch
#define EPSF  1e-5f

typedef float fvec4 __attribute__((ext_vector_type(4)));

// ws layout (floats): [0,4096)     s_part[b*64+c]
//                     [4096,8192)  ss_part[b*64+c]
// (fully overwritten by cn_stats every call -> no zeroing, no atomics)

__global__ __launch_bounds__(256) void cn_stats(const float* __restrict__ x,
                                                float* __restrict__ ws) {
    int p = blockIdx.x;            // plane index = b*NCH + c
    const fvec4* xp = (const fvec4*)(x + (size_t)p * HW);
    float s = 0.0f, ss = 0.0f;
    for (int i = threadIdx.x; i < HW4; i += 256) {
        fvec4 v = xp[i];
        s  += v.x + v.y + v.z + v.w;
        ss += v.x * v.x + v.y * v.y + v.z * v.z + v.w * v.w;
    }
    #pragma unroll
    for (int off = 32; off > 0; off >>= 1) {
        s  += __shfl_down(s, off, 64);
        ss += __shfl_down(ss, off, 64);
    }
    __shared__ float sh[8];
    int lane = threadIdx.x & 63;
    int wave = threadIdx.x >> 6;
    if (lane == 0) { sh[wave] = s; sh[4 + wave] = ss; }
    __syncthreads();
    if (threadIdx.x == 0) {
        ws[p]        = sh[0] + sh[1] + sh[2] + sh[3];
        ws[4096 + p] = sh[4] + sh[5] + sh[6] + sh[7];
    }
}

__global__ __launch_bounds__(256) void cn_norm(const float* __restrict__ x,
                                               const int* __restrict__ labels,
                                               const float* __restrict__ rmean,
                                               const float* __restrict__ rvar,
                                               const float* __restrict__ wgt,
                                               const float* __restrict__ bia,
                                               const float* __restrict__ ws,
                                               float* __restrict__ out) {
    int p = blockIdx.x;
    int b = p >> 6;
    int c = p & 63;
    __shared__ float sh_scale, sh_shift;
    if (threadIdx.x < 64) {
        int t = threadIdx.x;
        int g  = labels[b];         // this sample's cluster
        int lb = labels[t];         // lane t inspects sample t
        bool m = (lb == g);
        float s   = m ? ws[t * NCH + c]        : 0.0f;
        float ss  = m ? ws[4096 + t * NCH + c] : 0.0f;
        float cnt = m ? 1.0f : 0.0f;
        #pragma unroll
        for (int off = 32; off > 0; off >>= 1) {
            s   += __shfl_down(s,   off, 64);
            ss  += __shfl_down(ss,  off, 64);
            cnt += __shfl_down(cnt, off, 64);
        }
        if (t == 0) {
            float N    = cnt * (float)HW;
            float mean = s / fmaxf(N, 1.0f);
            float var  = (ss - N * mean * mean) / fmaxf(N - 1.0f, 1.0f);
            float mu   = 0.2f * mean + 0.8f * rmean[c];
            float vb   = 0.2f * var  + 0.8f * rvar[c];
            float scale = rsqrtf(vb + EPSF) * wgt[c];
            sh_scale = scale;
            sh_shift = bia[c] - mu * scale;
        }
    }
    __syncthreads();
    float scale = sh_scale;
    float shift = sh_shift;
    const fvec4* xp = (const fvec4*)(x + (size_t)p * HW);
    fvec4*       op = (fvec4*)(out + (size_t)p * HW);
    for (int i = threadIdx.x; i < HW4; i += 256) {
        fvec4 v = xp[i];
        fvec4 o;
        o.x = v.x * scale + shift;
        o.y = v.y * scale + shift;
        o.z = v.z * scale + shift;
        o.w = v.w * scale + shift;
        __builtin_nontemporal_store(o, &op[i]);
    }
}

extern "C" void kernel_launch(void* const* d_in, const int* in_sizes, int n_in,
                              void* d_out, int out_size, void* d_ws, size_t ws_size,
                              hipStream_t stream) {
    const float* x      = (const float*)d_in[0];
    const float* rmean  = (const float*)d_in[1];
    const float* rvar   = (const float*)d_in[2];
    const float* wgt    = (const float*)d_in[3];
    const float* bia    = (const float*)d_in[4];
    const int*   labels = (const int*)d_in[5];
    float* out = (float*)d_out;
    float* ws  = (float*)d_ws;

    const int planes = NB * NCH; // 4096

    cn_stats<<<planes, 256, 0, stream>>>(x, ws);
    cn_norm<<<planes, 256, 0, stream>>>(x, labels, rmean, rvar, wgt, bia, ws, out);
}